// Round 13
// baseline (400.199 us; speedup 1.0000x reference)
//
#include <hip/hip_runtime.h>

typedef __bf16 bf16x4 __attribute__((ext_vector_type(4)));
typedef __bf16 bf16x8 __attribute__((ext_vector_type(8)));
typedef float f32x16 __attribute__((ext_vector_type(16)));

// ---- workspace layout (bf16 element offsets), FRAGMENT-ORDERED weights ----
// A wave's weight frag for (n-tile, k-block) is 64 lanes x 16 B = 1 KB contig:
//   elem (lane, j) at ((nt*NKBLK + kk)*64 + lane)*8 + j
//   encodes n = nt*32 + (lane&31), k = kk*16 + (lane>>5)*8 + j
#define W0F_OFF 0                 // 16 nt x 1 kk  x 64 x 8  = 8192
#define W1F_OFF 8192              // 16 nt x 32 kk x 64 x 8  = 262144
#define W2F_OFF (8192 + 262144)   // 5 nt  x 32 kk x 64 x 8  = 81920 (n>=136 zero)
#define PREP_TOTAL (8192 + 262144 + 81920)

__global__ void prep_weights(const float* __restrict__ W0,
                             const float* __restrict__ W1,
                             const float* __restrict__ W2,
                             __bf16* __restrict__ ws) {
    int t = blockIdx.x * 256 + threadIdx.x;
    if (t < 8192) {
        int j = t & 7, lane = (t >> 3) & 63, nt = t >> 9;
        int n = nt * 32 + (lane & 31);
        int k = (lane >> 5) * 8 + j;              // < 16
        ws[W0F_OFF + t] = (__bf16)W0[k * 512 + n];
    } else if (t < 8192 + 262144) {
        int u = t - 8192;
        int j = u & 7, lane = (u >> 3) & 63;
        int x = u >> 9;                            // nt*32 + kk
        int kk = x & 31, nt = x >> 5;
        int n = nt * 32 + (lane & 31);
        int k = kk * 16 + (lane >> 5) * 8 + j;
        ws[W1F_OFF + u] = (__bf16)W1[k * 512 + n];
    } else if (t < PREP_TOTAL) {
        int v = t - (8192 + 262144);
        int j = v & 7, lane = (v >> 3) & 63;
        int x = v >> 9;                            // nt*32 + kk
        int kk = x & 31, nt = x >> 5;
        int n = nt * 32 + (lane & 31);
        int k = kk * 16 + (lane >> 5) * 8 + j;
        ws[W2F_OFF + v] = (n < 136) ? (__bf16)W2[k * 136 + n] : (__bf16)0.0f;
    }
}

__device__ __forceinline__ float fast_tanh(float x) {
#if __has_builtin(__builtin_amdgcn_exp2f)
    float e = __builtin_amdgcn_exp2f(x * 2.885390081777926f);
#else
    float e = exp2f(x * 2.885390081777926f);
#endif
    return 1.0f - 2.0f * __builtin_amdgcn_rcpf(e + 1.0f);
}

// h LDS: [64][520] bf16 (rows 1040 B, 16B-aligned). b128 reads sit at the
// structural 8-cyc/wave LDS floor; no swizzle needed (R12 analysis).
#define HSTR 520
// net LDS: [64][140] f32 overlay (float4-aligned rows).
#define NSTR 140

// R13: R12 operand-swap structure, BM 32 -> 64. L2 audit: BM=32 streams
// 672 KB weights per 32 rows -> 10.75 MB/CU -> ~80 us L2 floor (measured 180).
// BM=64 halves weight bytes/row AND halves weight-load:MFMA ratio (each
// weight frag feeds 2 batch-tiles).
// Register model (validated R12: VGPR = in-flight ops + addr): in-flight
// bb 64 + aa 32 = 96 + addr ~12 -> ~108 arch + 128 AGPR acc = 236 <= 256 cap.
// Fragment maps (m74/m101):
//   W(A): n_out = lane&31, k = (lane>>5)*8 + j
//   act(B): batch = lane&31, k = (lane>>5)*8 + j
//   D: batch = lane&31, n_out = (reg&3) + 8*(reg>>2) + 4*(lane>>5)
__global__ __launch_bounds__(256, 2)
void fused_mlp_quad(const float* __restrict__ points,
                    const float* __restrict__ b0,
                    const float* __restrict__ b1,
                    const float* __restrict__ b2,
                    const __bf16* __restrict__ ws,
                    float* __restrict__ out) {
    __shared__ __align__(16) unsigned char lds_raw[66560];
    __bf16* h  = (__bf16*)lds_raw;   // [64][HSTR] bf16 (h0, then h1 in place)
    float* net = (float*)lds_raw;    // [64][NSTR] f32 overlay after phase 2

    const __bf16* w0f = ws + W0F_OFF;
    const __bf16* w1f = ws + W1F_OFF;
    const __bf16* w2f = ws + W2F_OFF;

    const int tid = threadIdx.x;
    const int w   = tid >> 6;     // wave 0..3
    const int l   = tid & 63;
    const int ln  = l & 31;       // batch row within tile / 32x32 lane index
    const int hi  = l >> 5;       // k-half
    const int row0 = blockIdx.x * 64;

    const int lofs = l * 8;       // lane offset within a 1KB fragment record

    // ---------- phase 0: h0 = tanh(x @ W0 + b0), K=16 = one MFMA step ----------
    {
        bf16x8 bx[2];
#pragma unroll
        for (int bt = 0; bt < 2; ++bt) {
            const float* src = points + (row0 + bt * 32 + ln) * 16 + hi * 8;
            float4 p0 = ((const float4*)src)[0];
            float4 p1 = ((const float4*)src)[1];
            bf16x8 v;
            v[0] = (__bf16)p0.x; v[1] = (__bf16)p0.y; v[2] = (__bf16)p0.z; v[3] = (__bf16)p0.w;
            v[4] = (__bf16)p1.x; v[5] = (__bf16)p1.y; v[6] = (__bf16)p1.z; v[7] = (__bf16)p1.w;
            bx[bt] = v;
        }
#pragma unroll
        for (int t = 0; t < 4; ++t) {
            const int ntg = w * 4 + t;
            bf16x8 wf = *(const bf16x8*)(w0f + ntg * 512 + lofs);
#pragma unroll
            for (int bt = 0; bt < 2; ++bt) {
                f32x16 acc = {};
                acc = __builtin_amdgcn_mfma_f32_32x32x16_bf16(wf, bx[bt], acc, 0, 0, 0);
#pragma unroll
                for (int rg = 0; rg < 4; ++rg) {
                    const int n0 = ntg * 32 + 8 * rg + 4 * hi;
                    float4 bias = *(const float4*)(b0 + n0);
                    bf16x4 v;
                    v[0] = (__bf16)fast_tanh(acc[4 * rg + 0] + bias.x);
                    v[1] = (__bf16)fast_tanh(acc[4 * rg + 1] + bias.y);
                    v[2] = (__bf16)fast_tanh(acc[4 * rg + 2] + bias.z);
                    v[3] = (__bf16)fast_tanh(acc[4 * rg + 3] + bias.w);
                    *(bf16x4*)(h + (bt * 32 + ln) * HSTR + n0) = v;
                }
            }
        }
    }
    __syncthreads();

    // ---------- phase 1: h1 = tanh(h0 @ W1 + b1) ----------
    // wave: 4 n-tiles x 2 batch-tiles; acc = 128 AGPR. Super-iter 2 kk:
    // 8 weight frags + 4 act frags -> 16 MFMAs (1 L2 stall per 16 MFMAs).
    f32x16 acc1[2][4] = {};   // [bt][nt]
    {
        const __bf16* arow0 = h + ln * HSTR + hi * 8;          // bt=0
        const __bf16* arow1 = h + (32 + ln) * HSTR + hi * 8;   // bt=1
        const __bf16* w1b0 = w1f + (w * 4 + 0) * 16384 + lofs;
        const __bf16* w1b1 = w1f + (w * 4 + 1) * 16384 + lofs;
        const __bf16* w1b2 = w1f + (w * 4 + 2) * 16384 + lofs;
        const __bf16* w1b3 = w1f + (w * 4 + 3) * 16384 + lofs;
        for (int ks = 0; ks < 16; ++ks) {
            bf16x8 aa[2][2], bb[2][4];
#pragma unroll
            for (int u = 0; u < 2; ++u) {
                const int kk = ks * 2 + u;
                const int vo = kk * 512;
                aa[u][0] = *(const bf16x8*)(arow0 + kk * 16);
                aa[u][1] = *(const bf16x8*)(arow1 + kk * 16);
                bb[u][0] = *(const bf16x8*)(w1b0 + vo);
                bb[u][1] = *(const bf16x8*)(w1b1 + vo);
                bb[u][2] = *(const bf16x8*)(w1b2 + vo);
                bb[u][3] = *(const bf16x8*)(w1b3 + vo);
            }
#pragma unroll
            for (int u = 0; u < 2; ++u) {
#pragma unroll
                for (int t = 0; t < 4; ++t) {
                    acc1[0][t] = __builtin_amdgcn_mfma_f32_32x32x16_bf16(bb[u][t], aa[u][0], acc1[0][t], 0, 0, 0);
                    acc1[1][t] = __builtin_amdgcn_mfma_f32_32x32x16_bf16(bb[u][t], aa[u][1], acc1[1][t], 0, 0, 0);
                }
            }
        }
    }
    __syncthreads();   // all h0 reads done; overwrite in place
#pragma unroll
    for (int t = 0; t < 4; ++t) {
#pragma unroll
        for (int bt = 0; bt < 2; ++bt) {
#pragma unroll
            for (int rg = 0; rg < 4; ++rg) {
                const int n0 = (w * 4 + t) * 32 + 8 * rg + 4 * hi;
                float4 bias = *(const float4*)(b1 + n0);
                bf16x4 v;
                v[0] = (__bf16)fast_tanh(acc1[bt][t][4 * rg + 0] + bias.x);
                v[1] = (__bf16)fast_tanh(acc1[bt][t][4 * rg + 1] + bias.y);
                v[2] = (__bf16)fast_tanh(acc1[bt][t][4 * rg + 2] + bias.z);
                v[3] = (__bf16)fast_tanh(acc1[bt][t][4 * rg + 3] + bias.w);
                *(bf16x4*)(h + (bt * 32 + ln) * HSTR + n0) = v;
            }
        }
    }
    __syncthreads();

    // ---------- phase 2: net = h1 @ W2 + b2 (N pad 160: 5 nt x 2 bt = 10 tiles) ----
    // balanced 3/3/2/2: w0:(w,0)(w,1)(4,0)  w1:(w,0)(w,1)(4,1)  w2/w3:(w,0)(w,1)
    f32x16 acc2[3] = {};
    const bool three = (w < 2);
    {
        const __bf16* arow0 = h + ln * HSTR + hi * 8;
        const __bf16* arow1 = h + (32 + ln) * HSTR + hi * 8;
        const __bf16* w2bA = w2f + w * 16384 + lofs;
        const __bf16* w2bB = w2f + 4 * 16384 + lofs;
        for (int ks = 0; ks < 16; ++ks) {
            bf16x8 aa[2][2], wA[2], wB[2];
#pragma unroll
            for (int u = 0; u < 2; ++u) {
                const int kk = ks * 2 + u;
                const int vo = kk * 512;
                aa[u][0] = *(const bf16x8*)(arow0 + kk * 16);
                aa[u][1] = *(const bf16x8*)(arow1 + kk * 16);
                wA[u] = *(const bf16x8*)(w2bA + vo);
                if (three) wB[u] = *(const bf16x8*)(w2bB + vo);
            }
#pragma unroll
            for (int u = 0; u < 2; ++u) {
                acc2[0] = __builtin_amdgcn_mfma_f32_32x32x16_bf16(wA[u], aa[u][0], acc2[0], 0, 0, 0);
                acc2[1] = __builtin_amdgcn_mfma_f32_32x32x16_bf16(wA[u], aa[u][1], acc2[1], 0, 0, 0);
                if (three)
                    acc2[2] = __builtin_amdgcn_mfma_f32_32x32x16_bf16(wB[u], aa[u][w], acc2[2], 0, 0, 0);
            }
        }
    }
    __syncthreads();   // all h1 reads done; overwrite with net (fp32)
    {
#pragma unroll
        for (int bt = 0; bt < 2; ++bt) {
#pragma unroll
            for (int rg = 0; rg < 4; ++rg) {
                const int n0 = w * 32 + 8 * rg + 4 * hi;   // <= 127 < 136
                float4 bias = *(const float4*)(b2 + n0);
                float4 v;
                v.x = acc2[bt][4 * rg + 0] + bias.x;
                v.y = acc2[bt][4 * rg + 1] + bias.y;
                v.z = acc2[bt][4 * rg + 2] + bias.z;
                v.w = acc2[bt][4 * rg + 3] + bias.w;
                *(float4*)(net + (bt * 32 + ln) * NSTR + n0) = v;
            }
        }
        if (three) {
            // extra tile nt=4 (n 128..135): only rg==0 in range; rows bt=w
            const int n0 = 128 + 4 * hi;
            float4 bias = *(const float4*)(b2 + n0);
            float4 v;
            v.x = acc2[2][0] + bias.x;
            v.y = acc2[2][1] + bias.y;
            v.z = acc2[2][2] + bias.z;
            v.w = acc2[2][3] + bias.w;
            *(float4*)(net + (w * 32 + ln) * NSTR + n0) = v;
        }
    }
    __syncthreads();

    // ---------- phase 3: vals = ||M^T x||^2 + eps*||x||^2 ----------
    // 8 threads per row; 32 rows per pass, 2 passes
#pragma unroll
    for (int half = 0; half < 2; ++half) {
        const int r  = half * 32 + (tid >> 3);
        const int jg = tid & 7;
        const float* xp = points + (row0 + r) * 16;
        float xv[16];
#pragma unroll
        for (int i = 0; i < 4; ++i) {
            float4 v = ((const float4*)xp)[i];
            xv[i * 4 + 0] = v.x; xv[i * 4 + 1] = v.y;
            xv[i * 4 + 2] = v.z; xv[i * 4 + 3] = v.w;
        }
        float sumsq = 0.f;
#pragma unroll
        for (int i = 0; i < 16; ++i) sumsq += xv[i] * xv[i];
        float p = 0.f;
#pragma unroll
        for (int jj = 0; jj < 2; ++jj) {
            const int j = jg + jj * 8;
            float y = 0.f;
#pragma unroll
            for (int i = 0; i < 16; ++i) {
                float mv = net[r * NSTR + ((i * (i + 1)) >> 1) + j];
                y += (i >= j) ? mv * xv[i] : 0.f;
            }
            p += y * y;
        }
        p += __shfl_xor(p, 1);
        p += __shfl_xor(p, 2);
        p += __shfl_xor(p, 4);
        if (jg == 0) out[row0 + r] = p + 1e-6f * sumsq;
    }
}

extern "C" void kernel_launch(void* const* d_in, const int* in_sizes, int n_in,
                              void* d_out, int out_size, void* d_ws, size_t ws_size,
                              hipStream_t stream) {
    const float* points = (const float*)d_in[0];
    const float* W0 = (const float*)d_in[1];
    const float* b0 = (const float*)d_in[2];
    const float* W1 = (const float*)d_in[3];
    const float* b1 = (const float*)d_in[4];
    const float* W2 = (const float*)d_in[5];
    const float* b2 = (const float*)d_in[6];
    __bf16* ws = (__bf16*)d_ws;
    float* out = (float*)d_out;

    prep_weights<<<(PREP_TOTAL + 255) / 256, 256, 0, stream>>>(W0, W1, W2, ws);

    const int B = in_sizes[0] / 16;   // 131072
    fused_mlp_quad<<<B / 64, 256, 0, stream>>>(points, b0, b1, b2, ws, out);
}

// Round 14
// 189.877 us; speedup vs baseline: 2.1077x; 2.1077x over previous
//
#include <hip/hip_runtime.h>

typedef __bf16 bf16x4 __attribute__((ext_vector_type(4)));
typedef __bf16 bf16x8 __attribute__((ext_vector_type(8)));
typedef float f32x16 __attribute__((ext_vector_type(16)));

// ---- workspace layout (bf16 element offsets), FRAGMENT-ORDERED weights ----
// A wave's weight frag for (n-tile, k-block) is 64 lanes x 16 B = 1 KB contig:
//   elem (lane, j) at ((nt*NKBLK + kk)*64 + lane)*8 + j
//   encodes n = nt*32 + (lane&31), k = kk*16 + (lane>>5)*8 + j
#define W0F_OFF 0                 // 16 nt x 1 kk  x 64 x 8  = 8192
#define W1F_OFF 8192              // 16 nt x 32 kk x 64 x 8  = 262144
#define W2F_OFF (8192 + 262144)   // 5 nt  x 32 kk x 64 x 8  = 81920 (n>=136 zero)
#define PREP_TOTAL (8192 + 262144 + 81920)

__global__ void prep_weights(const float* __restrict__ W0,
                             const float* __restrict__ W1,
                             const float* __restrict__ W2,
                             __bf16* __restrict__ ws) {
    int t = blockIdx.x * 256 + threadIdx.x;
    if (t < 8192) {
        int j = t & 7, lane = (t >> 3) & 63, nt = t >> 9;
        int n = nt * 32 + (lane & 31);
        int k = (lane >> 5) * 8 + j;              // < 16
        ws[W0F_OFF + t] = (__bf16)W0[k * 512 + n];
    } else if (t < 8192 + 262144) {
        int u = t - 8192;
        int j = u & 7, lane = (u >> 3) & 63;
        int x = u >> 9;                            // nt*32 + kk
        int kk = x & 31, nt = x >> 5;
        int n = nt * 32 + (lane & 31);
        int k = kk * 16 + (lane >> 5) * 8 + j;
        ws[W1F_OFF + u] = (__bf16)W1[k * 512 + n];
    } else if (t < PREP_TOTAL) {
        int v = t - (8192 + 262144);
        int j = v & 7, lane = (v >> 3) & 63;
        int x = v >> 9;                            // nt*32 + kk
        int kk = x & 31, nt = x >> 5;
        int n = nt * 32 + (lane & 31);
        int k = kk * 16 + (lane >> 5) * 8 + j;
        ws[W2F_OFF + v] = (n < 136) ? (__bf16)W2[k * 136 + n] : (__bf16)0.0f;
    }
}

__device__ __forceinline__ float fast_tanh(float x) {
#if __has_builtin(__builtin_amdgcn_exp2f)
    float e = __builtin_amdgcn_exp2f(x * 2.885390081777926f);
#else
    float e = exp2f(x * 2.885390081777926f);
#endif
    return 1.0f - 2.0f * __builtin_amdgcn_rcpf(e + 1.0f);
}

// h LDS: [64][520] bf16 (rows 1040 B, 16B-aligned), imm-offset ds_read_b128.
#define HSTR 520
// net LDS: [64][140] f32 overlay (float4-aligned rows).
#define NSTR 140

// R14: BM=64 with 8 waves; wave tile = 2 nt x 2 bt -> acc = 64 AGPR (the
// R12-proven clean register shape; R13's acc=128 caused accvgpr-shuffle VALU).
// Why BM=64: per-CU vector-mem line rate ~60 B/cyc (m56) is the wall; BM=32
// needed 128 B/cyc (measured: R11/R12 stuck at ~25% MfmaUtil). BM=64 with
// one-fetch-per-nt halves demand to ~64 B/cyc -> MFMA and mem nearly balanced.
// Register audit: in-flight 4 wfrag + 4 afrag = 64 + addr ~20 -> ~88 arch
// + 64 acc = 152. (512,2) cap 256 -> no forced spill.
// Fragment maps (m74/m101):
//   W(A): n_out = lane&31, k = (lane>>5)*8 + j
//   act(B): batch = lane&31, k = (lane>>5)*8 + j
//   D: batch = lane&31, n_out = (reg&3) + 8*(reg>>2) + 4*(lane>>5)
__global__ __launch_bounds__(512, 2)
void fused_mlp_quad(const float* __restrict__ points,
                    const float* __restrict__ b0,
                    const float* __restrict__ b1,
                    const float* __restrict__ b2,
                    const __bf16* __restrict__ ws,
                    float* __restrict__ out) {
    __shared__ __align__(16) unsigned char lds_raw[66560];
    __bf16* h  = (__bf16*)lds_raw;   // [64][HSTR] bf16 (h0, then h1 in place)
    float* net = (float*)lds_raw;    // [64][NSTR] f32 overlay after phase 2

    const __bf16* w0f = ws + W0F_OFF;
    const __bf16* w1f = ws + W1F_OFF;
    const __bf16* w2f = ws + W2F_OFF;

    const int tid = threadIdx.x;
    const int w   = tid >> 6;     // wave 0..7
    const int l   = tid & 63;
    const int ln  = l & 31;       // batch row within tile / 32x32 lane index
    const int hi  = l >> 5;       // k-half
    const int row0 = blockIdx.x * 64;

    const int lofs = l * 8;       // lane offset within a 1KB fragment record

    // ---------- phase 0: h0 = tanh(x @ W0 + b0), K=16 = one MFMA step ----------
    {
        bf16x8 bx[2];
#pragma unroll
        for (int bt = 0; bt < 2; ++bt) {
            const float* src = points + (row0 + bt * 32 + ln) * 16 + hi * 8;
            float4 p0 = ((const float4*)src)[0];
            float4 p1 = ((const float4*)src)[1];
            bf16x8 v;
            v[0] = (__bf16)p0.x; v[1] = (__bf16)p0.y; v[2] = (__bf16)p0.z; v[3] = (__bf16)p0.w;
            v[4] = (__bf16)p1.x; v[5] = (__bf16)p1.y; v[6] = (__bf16)p1.z; v[7] = (__bf16)p1.w;
            bx[bt] = v;
        }
#pragma unroll
        for (int t = 0; t < 2; ++t) {
            const int ntg = w * 2 + t;
            bf16x8 wf = *(const bf16x8*)(w0f + ntg * 512 + lofs);
#pragma unroll
            for (int bt = 0; bt < 2; ++bt) {
                f32x16 acc = {};
                acc = __builtin_amdgcn_mfma_f32_32x32x16_bf16(wf, bx[bt], acc, 0, 0, 0);
#pragma unroll
                for (int rg = 0; rg < 4; ++rg) {
                    const int n0 = ntg * 32 + 8 * rg + 4 * hi;
                    float4 bias = *(const float4*)(b0 + n0);
                    bf16x4 v;
                    v[0] = (__bf16)fast_tanh(acc[4 * rg + 0] + bias.x);
                    v[1] = (__bf16)fast_tanh(acc[4 * rg + 1] + bias.y);
                    v[2] = (__bf16)fast_tanh(acc[4 * rg + 2] + bias.z);
                    v[3] = (__bf16)fast_tanh(acc[4 * rg + 3] + bias.w);
                    *(bf16x4*)(h + (bt * 32 + ln) * HSTR + n0) = v;
                }
            }
        }
    }
    __syncthreads();

    // ---------- phase 1: h1 = tanh(h0 @ W1 + b1) ----------
    // wave: 2 nt x 2 bt; acc = 64 AGPR. Super-iter 2 kk: 4 weight frags +
    // 4 act frags -> 8 MFMAs; each weight frag feeds 2 MFMAs.
    f32x16 acc1[2][2] = {};   // [bt][t]
    {
        const __bf16* arow0 = h + ln * HSTR + hi * 8;          // bt=0
        const __bf16* arow1 = h + (32 + ln) * HSTR + hi * 8;   // bt=1
        const __bf16* wb0 = w1f + (w * 2 + 0) * 16384 + lofs;
        const __bf16* wb1 = w1f + (w * 2 + 1) * 16384 + lofs;
        for (int ks = 0; ks < 16; ++ks) {
            bf16x8 aa[2][2], bb[2][2];
#pragma unroll
            for (int u = 0; u < 2; ++u) {
                const int kk = ks * 2 + u;
                const int vo = kk * 512;
                aa[u][0] = *(const bf16x8*)(arow0 + kk * 16);
                aa[u][1] = *(const bf16x8*)(arow1 + kk * 16);
                bb[u][0] = *(const bf16x8*)(wb0 + vo);
                bb[u][1] = *(const bf16x8*)(wb1 + vo);
            }
#pragma unroll
            for (int u = 0; u < 2; ++u) {
#pragma unroll
                for (int t = 0; t < 2; ++t) {
                    acc1[0][t] = __builtin_amdgcn_mfma_f32_32x32x16_bf16(bb[u][t], aa[u][0], acc1[0][t], 0, 0, 0);
                    acc1[1][t] = __builtin_amdgcn_mfma_f32_32x32x16_bf16(bb[u][t], aa[u][1], acc1[1][t], 0, 0, 0);
                }
            }
        }
    }
    __syncthreads();   // all h0 reads done; overwrite in place
#pragma unroll
    for (int t = 0; t < 2; ++t) {
#pragma unroll
        for (int bt = 0; bt < 2; ++bt) {
#pragma unroll
            for (int rg = 0; rg < 4; ++rg) {
                const int n0 = (w * 2 + t) * 32 + 8 * rg + 4 * hi;
                float4 bias = *(const float4*)(b1 + n0);
                bf16x4 v;
                v[0] = (__bf16)fast_tanh(acc1[bt][t][4 * rg + 0] + bias.x);
                v[1] = (__bf16)fast_tanh(acc1[bt][t][4 * rg + 1] + bias.y);
                v[2] = (__bf16)fast_tanh(acc1[bt][t][4 * rg + 2] + bias.z);
                v[3] = (__bf16)fast_tanh(acc1[bt][t][4 * rg + 3] + bias.w);
                *(bf16x4*)(h + (bt * 32 + ln) * HSTR + n0) = v;
            }
        }
    }
    __syncthreads();

    // ---------- phase 2: net = h1 @ W2 + b2 (N pad 160: 5 nt x 2 bt = 10 tiles) ----
    // wave w: tile (nt = w>>1, bt = w&1); waves 0,1 also tile (nt=4, bt=w).
    f32x16 acc2a = {}, acc2e = {};
    const int nt2 = w >> 1;
    const int bt2 = w & 1;
    const bool two = (w < 2);
    {
        const __bf16* arowA = h + (bt2 * 32 + ln) * HSTR + hi * 8;
        const __bf16* arowE = h + ((w & 1) * 32 + ln) * HSTR + hi * 8;  // bt=w for w<2
        const __bf16* wbA = w2f + nt2 * 16384 + lofs;
        const __bf16* wbE = w2f + 4 * 16384 + lofs;
        for (int ks = 0; ks < 16; ++ks) {
            bf16x8 aaA[2], wA[2], aaE[2], wE[2];
#pragma unroll
            for (int u = 0; u < 2; ++u) {
                const int kk = ks * 2 + u;
                const int vo = kk * 512;
                aaA[u] = *(const bf16x8*)(arowA + kk * 16);
                wA[u]  = *(const bf16x8*)(wbA + vo);
                if (two) {
                    aaE[u] = *(const bf16x8*)(arowE + kk * 16);
                    wE[u]  = *(const bf16x8*)(wbE + vo);
                }
            }
#pragma unroll
            for (int u = 0; u < 2; ++u) {
                acc2a = __builtin_amdgcn_mfma_f32_32x32x16_bf16(wA[u], aaA[u], acc2a, 0, 0, 0);
                if (two)
                    acc2e = __builtin_amdgcn_mfma_f32_32x32x16_bf16(wE[u], aaE[u], acc2e, 0, 0, 0);
            }
        }
    }
    __syncthreads();   // all h1 reads done; overwrite with net (fp32)
    {
#pragma unroll
        for (int rg = 0; rg < 4; ++rg) {
            const int n0 = nt2 * 32 + 8 * rg + 4 * hi;   // <= 127 < 136
            float4 bias = *(const float4*)(b2 + n0);
            float4 v;
            v.x = acc2a[4 * rg + 0] + bias.x;
            v.y = acc2a[4 * rg + 1] + bias.y;
            v.z = acc2a[4 * rg + 2] + bias.z;
            v.w = acc2a[4 * rg + 3] + bias.w;
            *(float4*)(net + (bt2 * 32 + ln) * NSTR + n0) = v;
        }
        if (two) {
            // extra tile nt=4 (n 128..135): only rg==0 in range (n0=128/132)
            const int n0 = 128 + 4 * hi;
            float4 bias = *(const float4*)(b2 + n0);
            float4 v;
            v.x = acc2e[0] + bias.x;
            v.y = acc2e[1] + bias.y;
            v.z = acc2e[2] + bias.z;
            v.w = acc2e[3] + bias.w;
            *(float4*)(net + (w * 32 + ln) * NSTR + n0) = v;
        }
    }
    __syncthreads();

    // ---------- phase 3: vals = ||M^T x||^2 + eps*||x||^2 ----------
    // 8 threads per row x 64 rows = 512 threads, single pass
    {
        const int r  = tid >> 3;
        const int jg = tid & 7;
        const float* xp = points + (row0 + r) * 16;
        float xv[16];
#pragma unroll
        for (int i = 0; i < 4; ++i) {
            float4 v = ((const float4*)xp)[i];
            xv[i * 4 + 0] = v.x; xv[i * 4 + 1] = v.y;
            xv[i * 4 + 2] = v.z; xv[i * 4 + 3] = v.w;
        }
        float sumsq = 0.f;
#pragma unroll
        for (int i = 0; i < 16; ++i) sumsq += xv[i] * xv[i];
        float p = 0.f;
#pragma unroll
        for (int jj = 0; jj < 2; ++jj) {
            const int j = jg + jj * 8;
            float y = 0.f;
#pragma unroll
            for (int i = 0; i < 16; ++i) {
                float mv = net[r * NSTR + ((i * (i + 1)) >> 1) + j];
                y += (i >= j) ? mv * xv[i] : 0.f;
            }
            p += y * y;
        }
        p += __shfl_xor(p, 1);
        p += __shfl_xor(p, 2);
        p += __shfl_xor(p, 4);
        if (jg == 0) out[row0 + r] = p + 1e-6f * sumsq;
    }
}

extern "C" void kernel_launch(void* const* d_in, const int* in_sizes, int n_in,
                              void* d_out, int out_size, void* d_ws, size_t ws_size,
                              hipStream_t stream) {
    const float* points = (const float*)d_in[0];
    const float* W0 = (const float*)d_in[1];
    const float* b0 = (const float*)d_in[2];
    const float* W1 = (const float*)d_in[3];
    const float* b1 = (const float*)d_in[4];
    const float* W2 = (const float*)d_in[5];
    const float* b2 = (const float*)d_in[6];
    __bf16* ws = (__bf16*)d_ws;
    float* out = (float*)d_out;

    prep_weights<<<(PREP_TOTAL + 255) / 256, 256, 0, stream>>>(W0, W1, W2, ws);

    const int B = in_sizes[0] / 16;   // 131072
    fused_mlp_quad<<<B / 64, 512, 0, stream>>>(points, b0, b1, b2, ws, out);
}